// Round 20
// baseline (454.452 us; speedup 1.0000x reference)
//
#include <hip/hip_runtime.h>
#include <hip/hip_bf16.h>
#include <math.h>

typedef __attribute__((ext_vector_type(4))) float floatx4;
typedef __attribute__((ext_vector_type(8))) __bf16 bfloatx8;
typedef __attribute__((ext_vector_type(8))) unsigned short ushortx8;

static __device__ __forceinline__ unsigned short f2bf(float f) {
  __hip_bfloat16 h = __float2bfloat16(f);
  return *reinterpret_cast<unsigned short*>(&h);
}

static __device__ __forceinline__ void gload16(const void* g, void* l) {
  __builtin_amdgcn_global_load_lds(
      (const __attribute__((address_space(1))) unsigned int*)g,
      (__attribute__((address_space(3))) unsigned int*)l, 16, 0, 0);
}

#define S_BARRIER() __builtin_amdgcn_s_barrier()
#define WAIT_VM(n)  do { asm volatile("s_waitcnt vmcnt(" #n ")" ::: "memory"); __builtin_amdgcn_sched_barrier(0); } while (0)

// ------------- transpose + cast: out[c][r] = bf16(in[r][c]) -------------
__global__ __launch_bounds__(256) void transpose_bf16_kernel(const float* __restrict__ in,
                                                             unsigned short* __restrict__ out,
                                                             int rows, int cols) {
  __shared__ float tile[32][33];
  int c0 = blockIdx.x * 32, r0 = blockIdx.y * 32;
  int tx = threadIdx.x, ty = threadIdx.y;
#pragma unroll
  for (int j = 0; j < 32; j += 8)
    tile[ty + j][tx] = in[(size_t)(r0 + ty + j) * cols + c0 + tx];
  __syncthreads();
#pragma unroll
  for (int j = 0; j < 32; j += 8)
    out[(size_t)(c0 + ty + j) * rows + r0 + tx] = f2bf(tile[tx][ty + j]);
}

// ------- lora_mid + x->bf16 fused, vectorized -------
__global__ __launch_bounds__(256) void lora_mid_convert_kernel(const float* __restrict__ x,
                                                               const float* __restrict__ a_down,
                                                               const int* __restrict__ idxp,
                                                               float* __restrict__ lmid,
                                                               unsigned short* __restrict__ Xb) {
  __shared__ float ad[1024 * 9];
  const float* A = a_down + (size_t)(*idxp) * (1024 * 8);
  int t = threadIdx.x;
  for (int i = t; i < 2048; i += 256) {
    float4 v = ((const float4*)A)[i];
    int row = i >> 1, p = (i & 1) * 4;
    ad[row * 9 + p] = v.x; ad[row * 9 + p + 1] = v.y;
    ad[row * 9 + p + 2] = v.z; ad[row * 9 + p + 3] = v.w;
  }
  __syncthreads();
  int wid = t >> 6, lane = t & 63;
  int row = blockIdx.x * 4 + wid;
  const float4* xr4 = (const float4*)(x + (size_t)row * 1024);
  ushort4* xbr4 = (ushort4*)(Xb + (size_t)row * 1024);
  float acc[8] = {0.f, 0.f, 0.f, 0.f, 0.f, 0.f, 0.f, 0.f};
#pragma unroll
  for (int c = 0; c < 4; ++c) {
    int i4 = c * 64 + lane;
    float4 xv = xr4[i4];
    ushort4 o;
    o.x = f2bf(xv.x); o.y = f2bf(xv.y); o.z = f2bf(xv.z); o.w = f2bf(xv.w);
    xbr4[i4] = o;
    const int kb = i4 * 4;
    const float xs[4] = {xv.x, xv.y, xv.z, xv.w};
#pragma unroll
    for (int j = 0; j < 4; ++j)
#pragma unroll
      for (int r = 0; r < 8; ++r) acc[r] += xs[j] * ad[(kb + j) * 9 + r];
  }
#pragma unroll
  for (int off = 32; off > 0; off >>= 1) {
#pragma unroll
    for (int r = 0; r < 8; ++r) acc[r] += __shfl_xor(acc[r], off);
  }
  if (lane == 0) {
    *(float4*)(lmid + (size_t)row * 8) = make_float4(acc[0], acc[1], acc[2], acc[3]);
    *(float4*)(lmid + (size_t)row * 8 + 4) = make_float4(acc[4], acc[5], acc[6], acc[7]);
  }
}

// ===== 256x256 8-phase K-loop (BK=64, 8 waves 2Mx4N, 128 KiB LDS dbuf), T2+T3+T4+T5 =====
// Buffer b at b*65536: A [2 halves x 16KB] at +0, B at +32768. Half h = rows h*128..h*128+127,
// stored [128 rows][128 B] linear; swizzle: col-16B-slot ^= (row&7) (involution on both the
// pre-swizzled global source col and ds_read addr; verified: slot(ks*4+kg) ^ (lr&7)).
// Wave (wm,wn): rows wm*128 (8 m-frags), cols wn*64 (4 n-frags); acc[8][4] = 128 VGPR ->
// needs launch_bounds(512,2) for the 256-VGPR cap (R6's spill was the 128 default cap).
// Quadrant phases per tile: (0,0)(0,1)(1,1)(1,0); bq0 kept live P1->P4 (no LDS B re-read).
// Reads: b.A at P1,P3; b.B at P1,P2 -> quiet: b.B after P2, b.A after P3.
// Stages (1 half/phase, 2 loads/thread): P1 A0(t1)->b1, P2 A1(t1)->b1, P3 B0(u0)->b0,
// P4 B1(u0)->b0, P5 A0(u0)->b0, P6 A1(u0)->b0, P7 B0(u1)->b1, P8 B1(u1)->b1.
// Drains: vmcnt(4) at P4 (drains B(t1)+A(t1), leaves B(u0)) and P8 (drains B,A(u0), leaves
// B(u1)). FIFO verified across prologue/steady/tail. NO explicit lgkm waits (m141 poison);
// single raw s_barrier per phase (R19-proven idiom); setprio around MFMA (T5).
template <int LD, int NKT>
static __device__ __forceinline__ void kloop8(const unsigned short* __restrict__ A,
                                              const unsigned short* __restrict__ B,
                                              size_t m0, size_t n0, char* smem,
                                              floatx4 (&acc)[8][4]) {
  const int t = threadIdx.x;
  const int w = t >> 6, lane = t & 63, lr = lane & 15, kg = lane >> 4;
  const int wm = w >> 2, wn = w & 3;
  const unsigned lswz = (unsigned)(lane & 7) << 4;
  const unsigned aRd = (unsigned)wm * 16384u;
  const unsigned bRd = 32768u + (unsigned)(wn >> 1) * 16384u;
  const int sr = t >> 3;
  const int scol = ((t & 7) ^ (sr & 7)) * 8;
  const unsigned short* gAs = A + (m0 + (size_t)sr) * LD + scol;
  const unsigned short* gBs = B + (n0 + (size_t)sr) * LD + scol;

#define STG_A(tau, h, bufb)                                                                     \
  do {                                                                                          \
    gload16(gAs + (size_t)((h)*128) * LD + (size_t)(tau)*64,                                    \
            smem + (bufb) + (unsigned)(h)*16384u + (unsigned)t * 16u);                          \
    gload16(gAs + (size_t)((h)*128 + 64) * LD + (size_t)(tau)*64,                               \
            smem + (bufb) + (unsigned)(h)*16384u + 8192u + (unsigned)t * 16u);                  \
  } while (0)
#define STG_B(tau, h, bufb)                                                                     \
  do {                                                                                          \
    gload16(gBs + (size_t)((h)*128) * LD + (size_t)(tau)*64,                                    \
            smem + (bufb) + 32768u + (unsigned)(h)*16384u + (unsigned)t * 16u);                 \
    gload16(gBs + (size_t)((h)*128 + 64) * LD + (size_t)(tau)*64,                               \
            smem + (bufb) + 32768u + (unsigned)(h)*16384u + 8192u + (unsigned)t * 16u);         \
  } while (0)

  bfloatx8 af[4][2], bq0[2][2], bq1[2][2];
#define LOAD_A(bufb, MH)                                                                        \
  do {                                                                                          \
    _Pragma("unroll") for (int mi = 0; mi < 4; ++mi)                                            \
        _Pragma("unroll") for (int ks = 0; ks < 2; ++ks)                                        \
            af[mi][ks] = *(const bfloatx8*)(smem + (bufb) + aRd +                               \
                (unsigned)(((MH)*4 + mi) * 16 + lr) * 128u +                                    \
                (((unsigned)ks * 64u + (unsigned)kg * 16u) ^ lswz));                            \
  } while (0)
#define LOAD_BQ(bufb, NH, dst)                                                                  \
  do {                                                                                          \
    _Pragma("unroll") for (int ni = 0; ni < 2; ++ni)                                            \
        _Pragma("unroll") for (int ks = 0; ks < 2; ++ks)                                        \
            dst[ni][ks] = *(const bfloatx8*)(smem + (bufb) + bRd +                              \
                (unsigned)((wn & 1) * 64 + ((NH)*2 + ni) * 16 + lr) * 128u +                    \
                (((unsigned)ks * 64u + (unsigned)kg * 16u) ^ lswz));                            \
  } while (0)
#define MFMA_Q(MH, NH, bq)                                                                      \
  do {                                                                                          \
    __builtin_amdgcn_s_setprio(1);                                                              \
    _Pragma("unroll") for (int mi = 0; mi < 4; ++mi)                                            \
        _Pragma("unroll") for (int ni = 0; ni < 2; ++ni)                                        \
            _Pragma("unroll") for (int ks = 0; ks < 2; ++ks)                                    \
                acc[(MH)*4 + mi][(NH)*2 + ni] = __builtin_amdgcn_mfma_f32_16x16x32_bf16(        \
                    af[mi][ks], bq[ni][ks], acc[(MH)*4 + mi][(NH)*2 + ni], 0, 0, 0);            \
    __builtin_amdgcn_s_setprio(0);                                                              \
  } while (0)

  // prologue: tile0 (B,A) -> b0; B(tile1) -> b1; drain tile0 (leave B(1)'s 4)
  STG_B(0, 0, 0u); STG_B(0, 1, 0u); STG_A(0, 0, 0u); STG_A(0, 1, 0u);
  STG_B(1, 0, 65536u); STG_B(1, 1, 65536u);
  WAIT_VM(4);
  S_BARRIER();

  const int nit = NKT / 2;
#pragma unroll 1
  for (int it = 0; it < nit; ++it) {
    const int t1 = 2 * it + 1, u0 = 2 * it + 2, u1 = 2 * it + 3;
    const bool s0 = u0 < NKT, s1 = u1 < NKT;
    // P1 (0,0) on b0
    LOAD_A(0u, 0); LOAD_BQ(0u, 0, bq0); STG_A(t1, 0, 65536u);
    MFMA_Q(0, 0, bq0); S_BARRIER();
    // P2 (0,1)
    LOAD_BQ(0u, 1, bq1); STG_A(t1, 1, 65536u);
    MFMA_Q(0, 1, bq1); S_BARRIER();
    // P3 (1,1) — b0.B quiet after P2
    LOAD_A(0u, 1); if (s0) STG_B(u0, 0, 0u);
    MFMA_Q(1, 1, bq1); S_BARRIER();
    // P4 (1,0) — drain: normal vmcnt(4) (leaves B(u0)); tail vmcnt(0) (drains A(t1))
    if (s0) STG_B(u0, 1, 0u);
    MFMA_Q(1, 0, bq0);
    if (s0) { WAIT_VM(4); } else { WAIT_VM(0); }
    S_BARRIER();
    // P5 (0,0) on b1 — b0.A quiet after P3
    LOAD_A(65536u, 0); LOAD_BQ(65536u, 0, bq0); if (s0) STG_A(u0, 0, 0u);
    MFMA_Q(0, 0, bq0); S_BARRIER();
    // P6 (0,1)
    LOAD_BQ(65536u, 1, bq1); if (s0) STG_A(u0, 1, 0u);
    MFMA_Q(0, 1, bq1); S_BARRIER();
    // P7 (1,1) — b1.B quiet after P6
    LOAD_A(65536u, 1); if (s1) STG_B(u1, 0, 65536u);
    MFMA_Q(1, 1, bq1); S_BARRIER();
    // P8 (1,0)
    if (s1) STG_B(u1, 1, 65536u);
    MFMA_Q(1, 0, bq0);
    if (s1) { WAIT_VM(4); }
    S_BARRIER();
  }
#undef MFMA_Q
#undef LOAD_BQ
#undef LOAD_A
#undef STG_B
#undef STG_A
}

// epilogue sE stride (f32): 260 -> row rotates banks by 4; write conflicts 2-way; 16B-aligned
#define ESTR2 260

// ------- GEMM1: H = gelu(Xb . W1T^T + b1), bf16 out. 512 thr, grid 1024, 128KB LDS -------
__global__ __launch_bounds__(512, 2) void gemm1_gelu_kernel(const unsigned short* __restrict__ A,
                                                            const unsigned short* __restrict__ B,
                                                            const float* __restrict__ bias,
                                                            unsigned short* __restrict__ H) {
  extern __shared__ char smem[];
  const int t = threadIdx.x;
  const int w = t >> 6, lane = t & 63, lr = lane & 15, kg = lane >> 4;
  const int wm = w >> 2, wn = w & 3;

  // per-XCD squares: M-tiles 64, N-tiles 16; xcd owns 8 mt x 16 nt in two 8x8 squares
  const int bid = blockIdx.x;
  const int xcd = bid & 7, j = bid >> 3;  // j 0..127
  const int sq = j >> 6, i = j & 63;      // sq 0..1
  const size_t m0 = (size_t)(xcd * 8 + (i & 7)) * 256;
  const size_t n0 = (size_t)(sq * 8 + (i >> 3)) * 256;

  floatx4 acc[8][4] = {};
  kloop8<1024, 16>(A, B, m0, n0, smem, acc);

  __syncthreads();
  float* sE = (float*)smem;  // [64][ESTR2]
  const int erow = t >> 3, ec0 = (t & 7) * 32;
#pragma unroll
  for (int r4 = 0; r4 < 4; ++r4) {
    if (wm == (r4 >> 1)) {
      const int q = r4 & 1;
#pragma unroll
      for (int mi = 0; mi < 4; ++mi)
#pragma unroll
        for (int ni = 0; ni < 4; ++ni)
#pragma unroll
          for (int rr = 0; rr < 4; ++rr)
            sE[(mi * 16 + kg * 4 + rr) * ESTR2 + wn * 64 + ni * 16 + lr] = acc[q * 4 + mi][ni][rr];
    }
    __syncthreads();
    const size_t gm = m0 + r4 * 64 + erow;
    const int gc = (int)n0 + ec0;
    const float* src = sE + erow * ESTR2 + ec0;
    alignas(16) unsigned short pk[32];
#pragma unroll
    for (int i2 = 0; i2 < 32; ++i2) {
      float v = src[i2] + bias[gc + i2];
      float g = 0.5f * v * (1.0f + erff(v * 0.70710678118654752440f));
      pk[i2] = f2bf(g);
    }
#pragma unroll
    for (int i2 = 0; i2 < 32; i2 += 8)
      *(ushortx8*)(H + gm * 4096 + gc + i2) = *(const ushortx8*)&pk[i2];
    __syncthreads();
  }
}

// --- GEMM2: OUT = H . W2T^T + b2 + lora, f32 out. 512 thr, grid 256, 128KB LDS ---
__global__ __launch_bounds__(512, 2) void gemm2_out_kernel(const unsigned short* __restrict__ A,
                                                           const unsigned short* __restrict__ B,
                                                           const float* __restrict__ bias,
                                                           const float* __restrict__ lmid,
                                                           const float* __restrict__ a_up,
                                                           const int* __restrict__ idxp,
                                                           float* __restrict__ OUT) {
  extern __shared__ char smem[];
  const int t = threadIdx.x;
  const int w = t >> 6, lane = t & 63, lr = lane & 15, kg = lane >> 4;
  const int wm = w >> 2, wn = w & 3;

  // M-tiles 64, N-tiles 4: xcd owns 8 mt x 4 nt
  const int bid = blockIdx.x;
  const int xcd = bid & 7, j = bid >> 3;  // j 0..31
  const size_t m0 = (size_t)(xcd * 8 + (j >> 2)) * 256;
  const size_t n0 = (size_t)(j & 3) * 256;

  floatx4 acc[8][4] = {};
  kloop8<4096, 64>(A, B, m0, n0, smem, acc);

  __syncthreads();
  float* sE = (float*)smem;
  const float* aup = a_up + (size_t)(*idxp) * 8192;
  const int erow = t >> 3, ec0 = (t & 7) * 32;
#pragma unroll
  for (int r4 = 0; r4 < 4; ++r4) {
    if (wm == (r4 >> 1)) {
      const int q = r4 & 1;
#pragma unroll
      for (int mi = 0; mi < 4; ++mi)
#pragma unroll
        for (int ni = 0; ni < 4; ++ni)
#pragma unroll
          for (int rr = 0; rr < 4; ++rr)
            sE[(mi * 16 + kg * 4 + rr) * ESTR2 + wn * 64 + ni * 16 + lr] = acc[q * 4 + mi][ni][rr];
    }
    __syncthreads();
    const size_t gm = m0 + r4 * 64 + erow;
    const int gc = (int)n0 + ec0;
    const float* src = sE + erow * ESTR2 + ec0;
    alignas(16) float lmv[8];
    *(float4*)&lmv[0] = *(const float4*)(lmid + gm * 8);
    *(float4*)&lmv[4] = *(const float4*)(lmid + gm * 8 + 4);
    alignas(16) float v[32];
#pragma unroll
    for (int i2 = 0; i2 < 32; ++i2) v[i2] = src[i2] + bias[gc + i2];
#pragma unroll
    for (int r = 0; r < 8; ++r) {
      const float lw = lmv[r];
      const float* ar = aup + r * 1024 + gc;
#pragma unroll
      for (int i2 = 0; i2 < 32; ++i2) v[i2] += lw * ar[i2];
    }
#pragma unroll
    for (int i2 = 0; i2 < 32; i2 += 4)
      *(float4*)(OUT + gm * 1024 + gc + i2) = *(const float4*)&v[i2];
    __syncthreads();
  }
}

extern "C" void kernel_launch(void* const* d_in, const int* in_sizes, int n_in,
                              void* d_out, int out_size, void* d_ws, size_t ws_size,
                              hipStream_t stream) {
  const float* x      = (const float*)d_in[0];
  const float* w1     = (const float*)d_in[1];
  const float* b1     = (const float*)d_in[2];
  const float* w2     = (const float*)d_in[3];
  const float* b2     = (const float*)d_in[4];
  const float* a_down = (const float*)d_in[5];
  const float* a_up   = (const float*)d_in[6];
  const int*   idx    = (const int*)d_in[7];
  float* out = (float*)d_out;

  char* ws = (char*)d_ws;
  unsigned short* Xb  = (unsigned short*)(ws);              // 16384x1024 bf16 = 32 MiB
  unsigned short* W1T = (unsigned short*)(ws + 33554432);   // 4096x1024 bf16 = 8 MiB
  unsigned short* W2T = (unsigned short*)(ws + 41943040);   // 1024x4096 bf16 = 8 MiB
  float*          LMID = (float*)(ws + 50331648);           // 16384x8 f32 = 0.5 MiB
  unsigned short* H   = (unsigned short*)(ws + 50855936);   // 16384x4096 bf16 = 128 MiB

  (void)hipFuncSetAttribute((const void*)gemm1_gelu_kernel, hipFuncAttributeMaxDynamicSharedMemorySize, 131072);
  (void)hipFuncSetAttribute((const void*)gemm2_out_kernel, hipFuncAttributeMaxDynamicSharedMemorySize, 131072);

  transpose_bf16_kernel<<<dim3(128, 32), dim3(32, 8), 0, stream>>>(w1, W1T, 1024, 4096);
  transpose_bf16_kernel<<<dim3(32, 128), dim3(32, 8), 0, stream>>>(w2, W2T, 4096, 1024);
  lora_mid_convert_kernel<<<4096, 256, 0, stream>>>(x, a_down, idx, LMID, Xb);
  gemm1_gelu_kernel<<<1024, 512, 131072, stream>>>(Xb, W1T, b1, H);
  gemm2_out_kernel<<<256, 512, 131072, stream>>>(H, W2T, b2, LMID, a_up, idx, out);
}

// Round 21
// 417.629 us; speedup vs baseline: 1.0882x; 1.0882x over previous
//
#include <hip/hip_runtime.h>
#include <hip/hip_bf16.h>
#include <math.h>

typedef __attribute__((ext_vector_type(4))) float floatx4;
typedef __attribute__((ext_vector_type(8))) __bf16 bfloatx8;
typedef __attribute__((ext_vector_type(8))) unsigned short ushortx8;

static __device__ __forceinline__ unsigned short f2bf(float f) {
  __hip_bfloat16 h = __float2bfloat16(f);
  return *reinterpret_cast<unsigned short*>(&h);
}

static __device__ __forceinline__ void gload16(const void* g, void* l) {
  __builtin_amdgcn_global_load_lds(
      (const __attribute__((address_space(1))) unsigned int*)g,
      (__attribute__((address_space(3))) unsigned int*)l, 16, 0, 0);
}

#define S_BARRIER() __builtin_amdgcn_s_barrier()
#define WAIT_VM(n)  do { asm volatile("s_waitcnt vmcnt(" #n ")" ::: "memory"); __builtin_amdgcn_sched_barrier(0); } while (0)

// sE row stride (f32) for GEMM epilogues. 128 made row*stride = 0 mod 32 banks ->
// 4-way write / 8-way read conflicts; epilogue conflicts were ~55us of gemm1 (R18 PMC:
// conflicts scale with block count, not K-steps). 132: writes 2-way (free), reads 4-way.
// 128*132*4 = 67584 B <= 73728; 528 B/row keeps float4 16B alignment.
#define ESTR 132

// ------------- transpose + cast: out[c][r] = bf16(in[r][c]) -------------
__global__ __launch_bounds__(256) void transpose_bf16_kernel(const float* __restrict__ in,
                                                             unsigned short* __restrict__ out,
                                                             int rows, int cols) {
  __shared__ float tile[32][33];
  int c0 = blockIdx.x * 32, r0 = blockIdx.y * 32;
  int tx = threadIdx.x, ty = threadIdx.y;
#pragma unroll
  for (int j = 0; j < 32; j += 8)
    tile[ty + j][tx] = in[(size_t)(r0 + ty + j) * cols + c0 + tx];
  __syncthreads();
#pragma unroll
  for (int j = 0; j < 32; j += 8)
    out[(size_t)(c0 + ty + j) * rows + r0 + tx] = f2bf(tile[tx][ty + j]);
}

// ------- lora_mid + x->bf16 fused, vectorized (G13): float4 loads, ushort4 stores -------
__global__ __launch_bounds__(256) void lora_mid_convert_kernel(const float* __restrict__ x,
                                                               const float* __restrict__ a_down,
                                                               const int* __restrict__ idxp,
                                                               float* __restrict__ lmid,
                                                               unsigned short* __restrict__ Xb) {
  __shared__ float ad[1024 * 9];  // padded stride 9
  const float* A = a_down + (size_t)(*idxp) * (1024 * 8);
  int t = threadIdx.x;
  for (int i = t; i < 2048; i += 256) {
    float4 v = ((const float4*)A)[i];
    int row = i >> 1, p = (i & 1) * 4;
    ad[row * 9 + p] = v.x; ad[row * 9 + p + 1] = v.y;
    ad[row * 9 + p + 2] = v.z; ad[row * 9 + p + 3] = v.w;
  }
  __syncthreads();
  int wid = t >> 6, lane = t & 63;
  int row = blockIdx.x * 4 + wid;
  const float4* xr4 = (const float4*)(x + (size_t)row * 1024);
  ushort4* xbr4 = (ushort4*)(Xb + (size_t)row * 1024);
  float acc[8] = {0.f, 0.f, 0.f, 0.f, 0.f, 0.f, 0.f, 0.f};
#pragma unroll
  for (int c = 0; c < 4; ++c) {
    int i4 = c * 64 + lane;
    float4 xv = xr4[i4];
    ushort4 o;
    o.x = f2bf(xv.x); o.y = f2bf(xv.y); o.z = f2bf(xv.z); o.w = f2bf(xv.w);
    xbr4[i4] = o;
    const int kb = i4 * 4;
    const float xs[4] = {xv.x, xv.y, xv.z, xv.w};
#pragma unroll
    for (int j = 0; j < 4; ++j)
#pragma unroll
      for (int r = 0; r < 8; ++r) acc[r] += xs[j] * ad[(kb + j) * 9 + r];
  }
#pragma unroll
  for (int off = 32; off > 0; off >>= 1) {
#pragma unroll
    for (int r = 0; r < 8; ++r) acc[r] += __shfl_xor(acc[r], off);
  }
  if (lane == 0) {
    *(float4*)(lmid + (size_t)row * 8) = make_float4(acc[0], acc[1], acc[2], acc[3]);
    *(float4*)(lmid + (size_t)row * 8 + 4) = make_float4(acc[4], acc[5], acc[6], acc[7]);
  }
}

// ===== 8-wave 256x128 GEMM K-loop (BK=32), 3x24KiB rotation, T3+T4 (R17/R18-proven) =====

// ------- GEMM1: H = gelu(Xb . W1T^T + b1), bf16 out. 512 thr, grid 2048 -------
__global__ __launch_bounds__(512) void gemm1_gelu_kernel(const unsigned short* __restrict__ A,
                                                         const unsigned short* __restrict__ B,
                                                         const float* __restrict__ bias,
                                                         unsigned short* __restrict__ H) {
  extern __shared__ char smem[];  // 73728 B
  const int t = threadIdx.x;
  const int w = t >> 6, lane = t & 63, lr = lane & 15, kg = lane >> 4;
  const int kgx = kg ^ ((lr >> 1) & 3);
  constexpr int LD = 1024, NKT = 32;

  // per-XCD 8x8 squares: M-tiles 64, N-tiles 32.
  const int bid = blockIdx.x;
  const int xcd = bid & 7, j = bid >> 3;   // j 0..255
  const int sq = j >> 6, i = j & 63;       // sq 0..3
  const size_t m0 = (size_t)(xcd * 8 + (i & 7)) * 256;
  const size_t n0 = (size_t)(sq * 8 + (i >> 3)) * 128;

  const int sr = w * 16 + (lane >> 2);
  const int scol = ((t & 3) ^ ((sr >> 1) & 3)) * 8;
  const unsigned short* gA0 = A + (m0 + sr) * LD + scol;
  const unsigned short* gA1 = A + (m0 + 128 + sr) * LD + scol;
  const unsigned short* gB = B + (n0 + sr) * LD + scol;
  const unsigned wOff = (unsigned)(w << 10);

#define STAGE1(bufb, ko)                              \
  do {                                                \
    gload16(gA0 + (ko), smem + (bufb) + wOff);        \
    gload16(gA1 + (ko), smem + (bufb) + 8192 + wOff); \
    gload16(gB + (ko), smem + (bufb) + 16384 + wOff); \
  } while (0)

  floatx4 acc[2][8] = {};

  STAGE1(0u, 0);
  STAGE1(24576u, 32);
  WAIT_VM(3);
  S_BARRIER();

  unsigned cur = 0u, stg = 49152u;
#pragma unroll 1
  for (int kt = 0; kt < NKT; ++kt) {
    if (kt + 2 < NKT) STAGE1(stg, (kt + 2) * 32);
    const unsigned short* As = (const unsigned short*)(smem + cur);
    const unsigned short* Bs = (const unsigned short*)(smem + cur + 16384);
    bfloatx8 af[2];
#pragma unroll
    for (int mi = 0; mi < 2; ++mi)
      af[mi] = *(const bfloatx8*)(As + (unsigned)(w * 32 + mi * 16 + lr) * 32 + (unsigned)kgx * 8);
    {
      bfloatx8 bfA[4];
#pragma unroll
      for (int ni = 0; ni < 4; ++ni)
        bfA[ni] = *(const bfloatx8*)(Bs + (unsigned)(ni * 16 + lr) * 32 + (unsigned)kgx * 8);
#pragma unroll
      for (int mi = 0; mi < 2; ++mi)
#pragma unroll
        for (int ni = 0; ni < 4; ++ni)
          acc[mi][ni] = __builtin_amdgcn_mfma_f32_16x16x32_bf16(af[mi], bfA[ni], acc[mi][ni], 0, 0, 0);
    }
    {
      bfloatx8 bfB[4];
#pragma unroll
      for (int ni = 0; ni < 4; ++ni)
        bfB[ni] = *(const bfloatx8*)(Bs + (unsigned)((ni + 4) * 16 + lr) * 32 + (unsigned)kgx * 8);
#pragma unroll
      for (int mi = 0; mi < 2; ++mi)
#pragma unroll
        for (int ni = 0; ni < 4; ++ni)
          acc[mi][4 + ni] = __builtin_amdgcn_mfma_f32_16x16x32_bf16(af[mi], bfB[ni], acc[mi][4 + ni], 0, 0, 0);
    }
    if (kt + 2 < NKT) { WAIT_VM(3); } else { WAIT_VM(0); }
    S_BARRIER();
    cur = (cur == 49152u) ? 0u : cur + 24576u;
    stg = (stg == 49152u) ? 0u : stg + 24576u;
  }
#undef STAGE1

  // epilogue: 2 rounds (mi), sE[128][ESTR] f32; per round 2 half-rounds of 16-wide gelu+bf16.
  __syncthreads();
  float* sE = (float*)smem;
  const int erow = t >> 3, ec0 = (t & 7) * 16;
#pragma unroll
  for (int mi = 0; mi < 2; ++mi) {
#pragma unroll
    for (int ni = 0; ni < 8; ++ni)
#pragma unroll
      for (int r = 0; r < 4; ++r)
        sE[(w * 16 + kg * 4 + r) * ESTR + ni * 16 + lr] = acc[mi][ni][r];
    __syncthreads();
#pragma unroll
    for (int h = 0; h < 2; ++h) {
      const int row = erow + h * 64;
      const size_t gm = m0 + (size_t)(row >> 4) * 32 + mi * 16 + (row & 15);
      const int gc = (int)n0 + ec0;
      const float* src = sE + row * ESTR + ec0;
      alignas(16) unsigned short pk[16];
#pragma unroll
      for (int i2 = 0; i2 < 16; ++i2) {
        float v = src[i2] + bias[gc + i2];
        float g = 0.5f * v * (1.0f + erff(v * 0.70710678118654752440f));
        pk[i2] = f2bf(g);
      }
      *(ushortx8*)(H + gm * 4096 + gc) = *(const ushortx8*)&pk[0];
      *(ushortx8*)(H + gm * 4096 + gc + 8) = *(const ushortx8*)&pk[8];
    }
    __syncthreads();
  }
}

// --- GEMM2: OUT = H . W2T^T + b2 + lora, f32 out. 512 thr, grid 512 ---
__global__ __launch_bounds__(512) void gemm2_out_kernel(const unsigned short* __restrict__ A,
                                                        const unsigned short* __restrict__ B,
                                                        const float* __restrict__ bias,
                                                        const float* __restrict__ lmid,
                                                        const float* __restrict__ a_up,
                                                        const int* __restrict__ idxp,
                                                        float* __restrict__ OUT) {
  extern __shared__ char smem[];  // 73728 B
  const int t = threadIdx.x;
  const int w = t >> 6, lane = t & 63, lr = lane & 15, kg = lane >> 4;
  const int kgx = kg ^ ((lr >> 1) & 3);
  constexpr int LD = 4096, NKT = 128;

  const int bid = blockIdx.x;
  const int xcd = bid & 7, j = bid >> 3;
  const size_t m0 = (size_t)(xcd * 8 + (j >> 3)) * 256;
  const size_t n0 = (size_t)(j & 7) * 128;

  const int sr = w * 16 + (lane >> 2);
  const int scol = ((t & 3) ^ ((sr >> 1) & 3)) * 8;
  const unsigned short* gA0 = A + (m0 + sr) * LD + scol;
  const unsigned short* gA1 = A + (m0 + 128 + sr) * LD + scol;
  const unsigned short* gB = B + (n0 + sr) * LD + scol;
  const unsigned wOff = (unsigned)(w << 10);

#define STAGE2(bufb, ko)                              \
  do {                                                \
    gload16(gA0 + (ko), smem + (bufb) + wOff);        \
    gload16(gA1 + (ko), smem + (bufb) + 8192 + wOff); \
    gload16(gB + (ko), smem + (bufb) + 16384 + wOff); \
  } while (0)

  floatx4 acc[2][8] = {};

  STAGE2(0u, 0);
  STAGE2(24576u, 32);
  WAIT_VM(3);
  S_BARRIER();

  unsigned cur = 0u, stg = 49152u;
#pragma unroll 1
  for (int kt = 0; kt < NKT; ++kt) {
    if (kt + 2 < NKT) STAGE2(stg, (kt + 2) * 32);
    const unsigned short* As = (const unsigned short*)(smem + cur);
    const unsigned short* Bs = (const unsigned short*)(smem + cur + 16384);
    bfloatx8 af[2];
#pragma unroll
    for (int mi = 0; mi < 2; ++mi)
      af[mi] = *(const bfloatx8*)(As + (unsigned)(w * 32 + mi * 16 + lr) * 32 + (unsigned)kgx * 8);
    {
      bfloatx8 bfA[4];
#pragma unroll
      for (int ni = 0; ni < 4; ++ni)
        bfA[ni] = *(const bfloatx8*)(Bs + (unsigned)(ni * 16 + lr) * 32 + (unsigned)kgx * 8);
#pragma unroll
      for (int mi = 0; mi < 2; ++mi)
#pragma unroll
        for (int ni = 0; ni < 4; ++ni)
          acc[mi][ni] = __builtin_amdgcn_mfma_f32_16x16x32_bf16(af[mi], bfA[ni], acc[mi][ni], 0, 0, 0);
    }
    {
      bfloatx8 bfB[4];
#pragma unroll
      for (int ni = 0; ni < 4; ++ni)
        bfB[ni] = *(const bfloatx8*)(Bs + (unsigned)((ni + 4) * 16 + lr) * 32 + (unsigned)kgx * 8);
#pragma unroll
      for (int mi = 0; mi < 2; ++mi)
#pragma unroll
        for (int ni = 0; ni < 4; ++ni)
          acc[mi][4 + ni] = __builtin_amdgcn_mfma_f32_16x16x32_bf16(af[mi], bfB[ni], acc[mi][4 + ni], 0, 0, 0);
    }
    if (kt + 2 < NKT) { WAIT_VM(3); } else { WAIT_VM(0); }
    S_BARRIER();
    cur = (cur == 49152u) ? 0u : cur + 24576u;
    stg = (stg == 49152u) ? 0u : stg + 24576u;
  }
#undef STAGE2

  __syncthreads();
  float* sE = (float*)smem;
  const float* aup = a_up + (size_t)(*idxp) * 8192;
  const int erow = t >> 3, ec0 = (t & 7) * 16;
#pragma unroll
  for (int mi = 0; mi < 2; ++mi) {
#pragma unroll
    for (int ni = 0; ni < 8; ++ni)
#pragma unroll
      for (int r = 0; r < 4; ++r)
        sE[(w * 16 + kg * 4 + r) * ESTR + ni * 16 + lr] = acc[mi][ni][r];
    __syncthreads();
#pragma unroll
    for (int h = 0; h < 2; ++h) {
      const int row = erow + h * 64;
      const size_t gm = m0 + (size_t)(row >> 4) * 32 + mi * 16 + (row & 15);
      const int gc = (int)n0 + ec0;
      const float* src = sE + row * ESTR + ec0;
      alignas(16) float lmv[8];
      *(float4*)&lmv[0] = *(const float4*)(lmid + gm * 8);
      *(float4*)&lmv[4] = *(const float4*)(lmid + gm * 8 + 4);
      alignas(16) float v[16];
#pragma unroll
      for (int i2 = 0; i2 < 16; ++i2) v[i2] = src[i2] + bias[gc + i2];
#pragma unroll
      for (int r = 0; r < 8; ++r) {
        const float lw = lmv[r];
        const float* ar = aup + r * 1024 + gc;
#pragma unroll
        for (int i2 = 0; i2 < 16; ++i2) v[i2] += lw * ar[i2];
      }
#pragma unroll
      for (int i2 = 0; i2 < 16; i2 += 4)
        *(float4*)(OUT + gm * 1024 + gc + i2) = *(const float4*)&v[i2];
    }
    __syncthreads();
  }
}

extern "C" void kernel_launch(void* const* d_in, const int* in_sizes, int n_in,
                              void* d_out, int out_size, void* d_ws, size_t ws_size,
                              hipStream_t stream) {
  const float* x      = (const float*)d_in[0];
  const float* w1     = (const float*)d_in[1];
  const float* b1     = (const float*)d_in[2];
  const float* w2     = (const float*)d_in[3];
  const float* b2     = (const float*)d_in[4];
  const float* a_down = (const float*)d_in[5];
  const float* a_up   = (const float*)d_in[6];
  const int*   idx    = (const int*)d_in[7];
  float* out = (float*)d_out;

  char* ws = (char*)d_ws;
  unsigned short* Xb  = (unsigned short*)(ws);              // 16384x1024 bf16 = 32 MiB
  unsigned short* W1T = (unsigned short*)(ws + 33554432);   // 4096x1024 bf16 = 8 MiB
  unsigned short* W2T = (unsigned short*)(ws + 41943040);   // 1024x4096 bf16 = 8 MiB
  float*          LMID = (float*)(ws + 50331648);           // 16384x8 f32 = 0.5 MiB
  unsigned short* H   = (unsigned short*)(ws + 50855936);   // 16384x4096 bf16 = 128 MiB

  (void)hipFuncSetAttribute((const void*)gemm1_gelu_kernel, hipFuncAttributeMaxDynamicSharedMemorySize, 73728);
  (void)hipFuncSetAttribute((const void*)gemm2_out_kernel, hipFuncAttributeMaxDynamicSharedMemorySize, 73728);

  transpose_bf16_kernel<<<dim3(128, 32), dim3(32, 8), 0, stream>>>(w1, W1T, 1024, 4096);
  transpose_bf16_kernel<<<dim3(32, 128), dim3(32, 8), 0, stream>>>(w2, W2T, 4096, 1024);
  lora_mid_convert_kernel<<<4096, 256, 0, stream>>>(x, a_down, idx, LMID, Xb);
  gemm1_gelu_kernel<<<2048, 512, 73728, stream>>>(Xb, W1T, b1, H);
  gemm2_out_kernel<<<512, 512, 73728, stream>>>(H, W2T, b2, LMID, a_up, idx, out);
}

// Round 22
// 412.851 us; speedup vs baseline: 1.1008x; 1.0116x over previous
//
#include <hip/hip_runtime.h>
#include <hip/hip_bf16.h>
#include <math.h>

typedef __attribute__((ext_vector_type(4))) float floatx4;
typedef __attribute__((ext_vector_type(8))) __bf16 bfloatx8;
typedef __attribute__((ext_vector_type(8))) unsigned short ushortx8;

static __device__ __forceinline__ unsigned short f2bf(float f) {
  __hip_bfloat16 h = __float2bfloat16(f);
  return *reinterpret_cast<unsigned short*>(&h);
}

static __device__ __forceinline__ void gload16(const void* g, void* l) {
  __builtin_amdgcn_global_load_lds(
      (const __attribute__((address_space(1))) unsigned int*)g,
      (__attribute__((address_space(3))) unsigned int*)l, 16, 0, 0);
}

#define S_BARRIER() __builtin_amdgcn_s_barrier()
#define WAIT_VM(n)  do { asm volatile("s_waitcnt vmcnt(" #n ")" ::: "memory"); __builtin_amdgcn_sched_barrier(0); } while (0)

// sE row stride (f32) for GEMM epilogues (R18/R19: epilogue bank conflicts; 132 = 2-way
// writes, 4-way reads, 16B-aligned rows; 128*132*4 = 67584 <= 73728).
#define ESTR 132

// ===== fused prep: [0,4096) w1-transpose, [4096,8192) w2-transpose, [8192,12288) lora =====
// Each sub-body is the byte-equivalent logic of its R19-proven standalone kernel; fusing
// into one dispatch removes 2 launch gaps and overlaps the three workloads' straggler tails.
__global__ __launch_bounds__(256) void prep_kernel(const float* __restrict__ w1,
                                                   const float* __restrict__ w2,
                                                   unsigned short* __restrict__ W1T,
                                                   unsigned short* __restrict__ W2T,
                                                   const float* __restrict__ x,
                                                   const float* __restrict__ a_down,
                                                   const int* __restrict__ idxp,
                                                   float* __restrict__ lmid,
                                                   unsigned short* __restrict__ Xb) {
  __shared__ __align__(16) char pmem[36864];
  const int bid = blockIdx.x;
  const int t = threadIdx.x;

  if (bid < 8192) {
    // transpose + cast: out[c][r] = bf16(in[r][c])
    const float* in;
    unsigned short* out;
    int rows, cols, bx, by;
    if (bid < 4096) {
      in = w1; out = W1T; rows = 1024; cols = 4096;
      bx = bid & 127; by = bid >> 7;          // grid (128, 32)
    } else {
      in = w2; out = W2T; rows = 4096; cols = 1024;
      const int b2 = bid - 4096;
      bx = b2 & 31; by = b2 >> 5;             // grid (32, 128)
    }
    float (*tile)[33] = (float(*)[33])pmem;
    const int c0 = bx * 32, r0 = by * 32;
    const int tx = t & 31, ty = t >> 5;
#pragma unroll
    for (int j = 0; j < 32; j += 8)
      tile[ty + j][tx] = in[(size_t)(r0 + ty + j) * cols + c0 + tx];
    __syncthreads();
#pragma unroll
    for (int j = 0; j < 32; j += 8)
      out[(size_t)(c0 + ty + j) * rows + r0 + tx] = f2bf(tile[tx][ty + j]);
    return;
  }

  // lora_mid + x->bf16 fused, vectorized
  float* ad = (float*)pmem;  // [1024*9] padded stride 9
  const float* A = a_down + (size_t)(*idxp) * (1024 * 8);
  for (int i = t; i < 2048; i += 256) {
    float4 v = ((const float4*)A)[i];
    int row = i >> 1, p = (i & 1) * 4;
    ad[row * 9 + p] = v.x; ad[row * 9 + p + 1] = v.y;
    ad[row * 9 + p + 2] = v.z; ad[row * 9 + p + 3] = v.w;
  }
  __syncthreads();
  const int j = bid - 8192;
  const int wid = t >> 6, lane = t & 63;
  const int row = j * 4 + wid;
  const float4* xr4 = (const float4*)(x + (size_t)row * 1024);
  ushort4* xbr4 = (ushort4*)(Xb + (size_t)row * 1024);
  float acc[8] = {0.f, 0.f, 0.f, 0.f, 0.f, 0.f, 0.f, 0.f};
#pragma unroll
  for (int c = 0; c < 4; ++c) {
    int i4 = c * 64 + lane;
    float4 xv = xr4[i4];
    ushort4 o;
    o.x = f2bf(xv.x); o.y = f2bf(xv.y); o.z = f2bf(xv.z); o.w = f2bf(xv.w);
    xbr4[i4] = o;
    const int kb = i4 * 4;
    const float xs[4] = {xv.x, xv.y, xv.z, xv.w};
#pragma unroll
    for (int jj = 0; jj < 4; ++jj)
#pragma unroll
      for (int r = 0; r < 8; ++r) acc[r] += xs[jj] * ad[(kb + jj) * 9 + r];
  }
#pragma unroll
  for (int off = 32; off > 0; off >>= 1) {
#pragma unroll
    for (int r = 0; r < 8; ++r) acc[r] += __shfl_xor(acc[r], off);
  }
  if (lane == 0) {
    *(float4*)(lmid + (size_t)row * 8) = make_float4(acc[0], acc[1], acc[2], acc[3]);
    *(float4*)(lmid + (size_t)row * 8 + 4) = make_float4(acc[4], acc[5], acc[6], acc[7]);
  }
}

// ===== 8-wave 256x128 GEMM K-loop (BK=32), 3x24KiB rotation, T3+T4 (R17-R21 proven) =====

// ------- GEMM1: H = gelu(Xb . W1T^T + b1), bf16 out. 512 thr, grid 2048 -------
__global__ __launch_bounds__(512) void gemm1_gelu_kernel(const unsigned short* __restrict__ A,
                                                         const unsigned short* __restrict__ B,
                                                         const float* __restrict__ bias,
                                                         unsigned short* __restrict__ H) {
  extern __shared__ char smem[];  // 73728 B
  const int t = threadIdx.x;
  const int w = t >> 6, lane = t & 63, lr = lane & 15, kg = lane >> 4;
  const int kgx = kg ^ ((lr >> 1) & 3);
  constexpr int LD = 1024, NKT = 32;

  // per-XCD 8x8 squares: M-tiles 64, N-tiles 32.
  const int bid = blockIdx.x;
  const int xcd = bid & 7, j = bid >> 3;   // j 0..255
  const int sq = j >> 6, i = j & 63;       // sq 0..3
  const size_t m0 = (size_t)(xcd * 8 + (i & 7)) * 256;
  const size_t n0 = (size_t)(sq * 8 + (i >> 3)) * 128;

  const int sr = w * 16 + (lane >> 2);
  const int scol = ((t & 3) ^ ((sr >> 1) & 3)) * 8;
  const unsigned short* gA0 = A + (m0 + sr) * LD + scol;
  const unsigned short* gA1 = A + (m0 + 128 + sr) * LD + scol;
  const unsigned short* gB = B + (n0 + sr) * LD + scol;
  const unsigned wOff = (unsigned)(w << 10);

#define STAGE1(bufb, ko)                              \
  do {                                                \
    gload16(gA0 + (ko), smem + (bufb) + wOff);        \
    gload16(gA1 + (ko), smem + (bufb) + 8192 + wOff); \
    gload16(gB + (ko), smem + (bufb) + 16384 + wOff); \
  } while (0)

  floatx4 acc[2][8] = {};

  STAGE1(0u, 0);
  STAGE1(24576u, 32);
  WAIT_VM(3);
  S_BARRIER();

  unsigned cur = 0u, stg = 49152u;
#pragma unroll 1
  for (int kt = 0; kt < NKT; ++kt) {
    if (kt + 2 < NKT) STAGE1(stg, (kt + 2) * 32);
    const unsigned short* As = (const unsigned short*)(smem + cur);
    const unsigned short* Bs = (const unsigned short*)(smem + cur + 16384);
    bfloatx8 af[2];
#pragma unroll
    for (int mi = 0; mi < 2; ++mi)
      af[mi] = *(const bfloatx8*)(As + (unsigned)(w * 32 + mi * 16 + lr) * 32 + (unsigned)kgx * 8);
    {
      bfloatx8 bfA[4];
#pragma unroll
      for (int ni = 0; ni < 4; ++ni)
        bfA[ni] = *(const bfloatx8*)(Bs + (unsigned)(ni * 16 + lr) * 32 + (unsigned)kgx * 8);
#pragma unroll
      for (int mi = 0; mi < 2; ++mi)
#pragma unroll
        for (int ni = 0; ni < 4; ++ni)
          acc[mi][ni] = __builtin_amdgcn_mfma_f32_16x16x32_bf16(af[mi], bfA[ni], acc[mi][ni], 0, 0, 0);
    }
    {
      bfloatx8 bfB[4];
#pragma unroll
      for (int ni = 0; ni < 4; ++ni)
        bfB[ni] = *(const bfloatx8*)(Bs + (unsigned)((ni + 4) * 16 + lr) * 32 + (unsigned)kgx * 8);
#pragma unroll
      for (int mi = 0; mi < 2; ++mi)
#pragma unroll
        for (int ni = 0; ni < 4; ++ni)
          acc[mi][4 + ni] = __builtin_amdgcn_mfma_f32_16x16x32_bf16(af[mi], bfB[ni], acc[mi][4 + ni], 0, 0, 0);
    }
    if (kt + 2 < NKT) { WAIT_VM(3); } else { WAIT_VM(0); }
    S_BARRIER();
    cur = (cur == 49152u) ? 0u : cur + 24576u;
    stg = (stg == 49152u) ? 0u : stg + 24576u;
  }
#undef STAGE1

  // epilogue: 2 rounds (mi), sE[128][ESTR] f32; per round 2 half-rounds of 16-wide gelu+bf16.
  __syncthreads();
  float* sE = (float*)smem;
  const int erow = t >> 3, ec0 = (t & 7) * 16;
#pragma unroll
  for (int mi = 0; mi < 2; ++mi) {
#pragma unroll
    for (int ni = 0; ni < 8; ++ni)
#pragma unroll
      for (int r = 0; r < 4; ++r)
        sE[(w * 16 + kg * 4 + r) * ESTR + ni * 16 + lr] = acc[mi][ni][r];
    __syncthreads();
#pragma unroll
    for (int h = 0; h < 2; ++h) {
      const int row = erow + h * 64;
      const size_t gm = m0 + (size_t)(row >> 4) * 32 + mi * 16 + (row & 15);
      const int gc = (int)n0 + ec0;
      const float* src = sE + row * ESTR + ec0;
      alignas(16) unsigned short pk[16];
#pragma unroll
      for (int i2 = 0; i2 < 16; ++i2) {
        float v = src[i2] + bias[gc + i2];
        float g = 0.5f * v * (1.0f + erff(v * 0.70710678118654752440f));
        pk[i2] = f2bf(g);
      }
      *(ushortx8*)(H + gm * 4096 + gc) = *(const ushortx8*)&pk[0];
      *(ushortx8*)(H + gm * 4096 + gc + 8) = *(const ushortx8*)&pk[8];
    }
    __syncthreads();
  }
}

// --- GEMM2: OUT = H . W2T^T + b2 + lora, f32 out. 512 thr, grid 512 ---
__global__ __launch_bounds__(512) void gemm2_out_kernel(const unsigned short* __restrict__ A,
                                                        const unsigned short* __restrict__ B,
                                                        const float* __restrict__ bias,
                                                        const float* __restrict__ lmid,
                                                        const float* __restrict__ a_up,
                                                        const int* __restrict__ idxp,
                                                        float* __restrict__ OUT) {
  extern __shared__ char smem[];  // 73728 B
  const int t = threadIdx.x;
  const int w = t >> 6, lane = t & 63, lr = lane & 15, kg = lane >> 4;
  const int kgx = kg ^ ((lr >> 1) & 3);
  constexpr int LD = 4096, NKT = 128;

  const int bid = blockIdx.x;
  const int xcd = bid & 7, j = bid >> 3;
  const size_t m0 = (size_t)(xcd * 8 + (j >> 3)) * 256;
  const size_t n0 = (size_t)(j & 7) * 128;

  const int sr = w * 16 + (lane >> 2);
  const int scol = ((t & 3) ^ ((sr >> 1) & 3)) * 8;
  const unsigned short* gA0 = A + (m0 + sr) * LD + scol;
  const unsigned short* gA1 = A + (m0 + 128 + sr) * LD + scol;
  const unsigned short* gB = B + (n0 + sr) * LD + scol;
  const unsigned wOff = (unsigned)(w << 10);

#define STAGE2(bufb, ko)                              \
  do {                                                \
    gload16(gA0 + (ko), smem + (bufb) + wOff);        \
    gload16(gA1 + (ko), smem + (bufb) + 8192 + wOff); \
    gload16(gB + (ko), smem + (bufb) + 16384 + wOff); \
  } while (0)

  floatx4 acc[2][8] = {};

  STAGE2(0u, 0);
  STAGE2(24576u, 32);
  WAIT_VM(3);
  S_BARRIER();

  unsigned cur = 0u, stg = 49152u;
#pragma unroll 1
  for (int kt = 0; kt < NKT; ++kt) {
    if (kt + 2 < NKT) STAGE2(stg, (kt + 2) * 32);
    const unsigned short* As = (const unsigned short*)(smem + cur);
    const unsigned short* Bs = (const unsigned short*)(smem + cur + 16384);
    bfloatx8 af[2];
#pragma unroll
    for (int mi = 0; mi < 2; ++mi)
      af[mi] = *(const bfloatx8*)(As + (unsigned)(w * 32 + mi * 16 + lr) * 32 + (unsigned)kgx * 8);
    {
      bfloatx8 bfA[4];
#pragma unroll
      for (int ni = 0; ni < 4; ++ni)
        bfA[ni] = *(const bfloatx8*)(Bs + (unsigned)(ni * 16 + lr) * 32 + (unsigned)kgx * 8);
#pragma unroll
      for (int mi = 0; mi < 2; ++mi)
#pragma unroll
        for (int ni = 0; ni < 4; ++ni)
          acc[mi][ni] = __builtin_amdgcn_mfma_f32_16x16x32_bf16(af[mi], bfA[ni], acc[mi][ni], 0, 0, 0);
    }
    {
      bfloatx8 bfB[4];
#pragma unroll
      for (int ni = 0; ni < 4; ++ni)
        bfB[ni] = *(const bfloatx8*)(Bs + (unsigned)((ni + 4) * 16 + lr) * 32 + (unsigned)kgx * 8);
#pragma unroll
      for (int mi = 0; mi < 2; ++mi)
#pragma unroll
        for (int ni = 0; ni < 4; ++ni)
          acc[mi][4 + ni] = __builtin_amdgcn_mfma_f32_16x16x32_bf16(af[mi], bfB[ni], acc[mi][4 + ni], 0, 0, 0);
    }
    if (kt + 2 < NKT) { WAIT_VM(3); } else { WAIT_VM(0); }
    S_BARRIER();
    cur = (cur == 49152u) ? 0u : cur + 24576u;
    stg = (stg == 49152u) ? 0u : stg + 24576u;
  }
#undef STAGE2

  __syncthreads();
  float* sE = (float*)smem;
  const float* aup = a_up + (size_t)(*idxp) * 8192;
  const int erow = t >> 3, ec0 = (t & 7) * 16;
#pragma unroll
  for (int mi = 0; mi < 2; ++mi) {
#pragma unroll
    for (int ni = 0; ni < 8; ++ni)
#pragma unroll
      for (int r = 0; r < 4; ++r)
        sE[(w * 16 + kg * 4 + r) * ESTR + ni * 16 + lr] = acc[mi][ni][r];
    __syncthreads();
#pragma unroll
    for (int h = 0; h < 2; ++h) {
      const int row = erow + h * 64;
      const size_t gm = m0 + (size_t)(row >> 4) * 32 + mi * 16 + (row & 15);
      const int gc = (int)n0 + ec0;
      const float* src = sE + row * ESTR + ec0;
      alignas(16) float lmv[8];
      *(float4*)&lmv[0] = *(const float4*)(lmid + gm * 8);
      *(float4*)&lmv[4] = *(const float4*)(lmid + gm * 8 + 4);
      alignas(16) float v[16];
#pragma unroll
      for (int i2 = 0; i2 < 16; ++i2) v[i2] = src[i2] + bias[gc + i2];
#pragma unroll
      for (int r = 0; r < 8; ++r) {
        const float lw = lmv[r];
        const float* ar = aup + r * 1024 + gc;
#pragma unroll
        for (int i2 = 0; i2 < 16; ++i2) v[i2] += lw * ar[i2];
      }
#pragma unroll
      for (int i2 = 0; i2 < 16; i2 += 4)
        *(float4*)(OUT + gm * 1024 + gc + i2) = *(const float4*)&v[i2];
    }
    __syncthreads();
  }
}

extern "C" void kernel_launch(void* const* d_in, const int* in_sizes, int n_in,
                              void* d_out, int out_size, void* d_ws, size_t ws_size,
                              hipStream_t stream) {
  const float* x      = (const float*)d_in[0];
  const float* w1     = (const float*)d_in[1];
  const float* b1     = (const float*)d_in[2];
  const float* w2     = (const float*)d_in[3];
  const float* b2     = (const float*)d_in[4];
  const float* a_down = (const float*)d_in[5];
  const float* a_up   = (const float*)d_in[6];
  const int*   idx    = (const int*)d_in[7];
  float* out = (float*)d_out;

  char* ws = (char*)d_ws;
  unsigned short* Xb  = (unsigned short*)(ws);              // 16384x1024 bf16 = 32 MiB
  unsigned short* W1T = (unsigned short*)(ws + 33554432);   // 4096x1024 bf16 = 8 MiB
  unsigned short* W2T = (unsigned short*)(ws + 41943040);   // 1024x4096 bf16 = 8 MiB
  float*          LMID = (float*)(ws + 50331648);           // 16384x8 f32 = 0.5 MiB
  unsigned short* H   = (unsigned short*)(ws + 50855936);   // 16384x4096 bf16 = 128 MiB

  (void)hipFuncSetAttribute((const void*)gemm1_gelu_kernel, hipFuncAttributeMaxDynamicSharedMemorySize, 73728);
  (void)hipFuncSetAttribute((const void*)gemm2_out_kernel, hipFuncAttributeMaxDynamicSharedMemorySize, 73728);

  prep_kernel<<<12288, 256, 0, stream>>>(w1, w2, W1T, W2T, x, a_down, idx, LMID, Xb);
  gemm1_gelu_kernel<<<2048, 512, 73728, stream>>>(Xb, W1T, b1, H);
  gemm2_out_kernel<<<512, 512, 73728, stream>>>(H, W2T, b2, LMID, a_up, idx, out);
}